// Round 1
// baseline (3652.926 us; speedup 1.0000x reference)
//
#include <hip/hip_runtime.h>

// ---------------------------------------------------------------------------
// GCN 3-layer forward:  h1 = relu(S(x@W1)+b1); h2 = relu(S(h1@W2)+b2);
//                       out = S(h2@W3)+b3   where S = weighted scatter-sum.
// Strategy (round 1 baseline):
//   - GEMM: fp32 vector-ALU, W staged fully in LDS (64KB), wave-per-row,
//     row held in 2 regs + __shfl broadcast. ReLU fused into input load.
//   - Aggregation: bias pre-fill of dest buffer, then wave-per-edge scatter
//     with hardware fp32 atomics (unsafeAtomicAdd -> global_atomic_add_f32).
// ---------------------------------------------------------------------------

__global__ __launch_bounds__(256) void fill_bias_kernel(
    float* __restrict__ buf, const float* __restrict__ bias,
    long total, int mask) {
  long i = (long)blockIdx.x * blockDim.x + threadIdx.x;
  long stride = (long)gridDim.x * blockDim.x;
  for (; i < total; i += stride) buf[i] = bias[i & mask];
}

// in: [nrows x 128], W: [128 x NC] row-major, out: [nrows x NC]
template <int NC, bool RELU>
__global__ __launch_bounds__(256) void gemm_kernel(
    const float* __restrict__ in, const float* __restrict__ W,
    float* __restrict__ out, int nrows) {
  constexpr int K = 128;
  __shared__ float Wlds[K * NC];
  // stage W (row-major, contiguous) via float4
  for (int i = threadIdx.x; i < K * NC / 4; i += 256) {
    ((float4*)Wlds)[i] = ((const float4*)W)[i];
  }
  __syncthreads();

  const int lane = threadIdx.x & 63;
  const int wave = threadIdx.x >> 6;
  const int r0 = blockIdx.x * 32 + wave * 8;  // 4 waves x 8 rows = 32 rows/block

  for (int i = 0; i < 8; ++i) {
    const int r = r0 + i;
    if (r >= nrows) return;
    float xa = in[(long)r * K + lane];
    float xb = in[(long)r * K + 64 + lane];
    if (RELU) { xa = fmaxf(xa, 0.f); xb = fmaxf(xb, 0.f); }
    float acc0 = 0.f, acc1 = 0.f;
#pragma unroll
    for (int k = 0; k < 64; ++k) {
      const float xv = __shfl(xa, k, 64);
      acc0 = fmaf(xv, Wlds[k * NC + lane], acc0);
      if (NC == 128) acc1 = fmaf(xv, Wlds[k * NC + 64 + lane], acc1);
    }
#pragma unroll
    for (int k = 0; k < 64; ++k) {
      const float xv = __shfl(xb, k, 64);
      acc0 = fmaf(xv, Wlds[(64 + k) * NC + lane], acc0);
      if (NC == 128) acc1 = fmaf(xv, Wlds[(64 + k) * NC + 64 + lane], acc1);
    }
    out[(long)r * NC + lane] = acc0;
    if (NC == 128) out[(long)r * NC + 64 + lane] = acc1;
  }
}

// agg[dst] += t[src] * w   (agg pre-filled with bias)
template <int F>
__global__ __launch_bounds__(256) void scatter_kernel(
    const float* __restrict__ t, const int* __restrict__ src,
    const int* __restrict__ dst, const float* __restrict__ ew,
    float* __restrict__ agg, int nedges) {
  const int lane = threadIdx.x & 63;
  const int wave0 = __builtin_amdgcn_readfirstlane(
      blockIdx.x * (blockDim.x >> 6) + (threadIdx.x >> 6));
  const int nwaves = gridDim.x * (blockDim.x >> 6);
  for (int e = wave0; e < nedges; e += nwaves) {
    const int s = src[e];
    const int d = dst[e];
    const float wt = ew[e];
    if (F == 128) {
      const float2 v = *(const float2*)&t[(long)s * 128 + lane * 2];
      unsafeAtomicAdd(&agg[(long)d * 128 + lane * 2], v.x * wt);
      unsafeAtomicAdd(&agg[(long)d * 128 + lane * 2 + 1], v.y * wt);
    } else {
      const float v = t[(long)s * 64 + lane];
      unsafeAtomicAdd(&agg[(long)d * 64 + lane], v * wt);
    }
  }
}

extern "C" void kernel_launch(void* const* d_in, const int* in_sizes, int n_in,
                              void* d_out, int out_size, void* d_ws, size_t ws_size,
                              hipStream_t stream) {
  const float* x  = (const float*)d_in[0];
  const int*   ei = (const int*)d_in[1];   // [2, E] (int32)
  const float* ew = (const float*)d_in[2];
  const float* W1 = (const float*)d_in[3];
  const float* b1 = (const float*)d_in[4];
  const float* W2 = (const float*)d_in[5];
  const float* b2 = (const float*)d_in[6];
  const float* W3 = (const float*)d_in[7];
  const float* b3 = (const float*)d_in[8];

  const int E = in_sizes[2];
  const int N = in_sizes[0] / 128;
  const int* src = ei;
  const int* dst = ei + E;

  float* A = (float*)d_ws;                 // N x 128 scratch (GEMM out)
  float* B = A + (size_t)N * 128;          // N x 128 scratch (agg / next in)
  float* out = (float*)d_out;              // N x 64

  const int gemm_blocks = (N + 31) / 32;

  // ---- layer 1: t = x@W1; B = b1 + S(t); (relu deferred into next GEMM)
  gemm_kernel<128, false><<<gemm_blocks, 256, 0, stream>>>(x, W1, A, N);
  fill_bias_kernel<<<2048, 256, 0, stream>>>(B, b1, (long)N * 128, 127);
  scatter_kernel<128><<<8192, 256, 0, stream>>>(A, src, dst, ew, B, E);

  // ---- layer 2: t = relu(B)@W2; B = b2 + S(t)
  gemm_kernel<128, true><<<gemm_blocks, 256, 0, stream>>>(B, W2, A, N);
  fill_bias_kernel<<<2048, 256, 0, stream>>>(B, b2, (long)N * 128, 127);
  scatter_kernel<128><<<8192, 256, 0, stream>>>(A, src, dst, ew, B, E);

  // ---- layer 3: t = relu(B)@W3; out = b3 + S(t)
  gemm_kernel<64, true><<<gemm_blocks, 256, 0, stream>>>(B, W3, A, N);
  fill_bias_kernel<<<2048, 256, 0, stream>>>(out, b3, (long)N * 64, 63);
  scatter_kernel<64><<<8192, 256, 0, stream>>>(A, src, dst, ew, out, E);
}

// Round 2
// 1167.114 us; speedup vs baseline: 3.1299x; 3.1299x over previous
//
#include <hip/hip_runtime.h>

// ---------------------------------------------------------------------------
// GCN 3-layer forward. Round 2: replace float-atomic scatter (1.6GB HBM RMW
// per layer, 20% BW, latency-bound) with on-device CSR build + wave-per-node
// gather-aggregate. Bias fused into gather init; ReLU fused into GEMM load.
// ---------------------------------------------------------------------------

constexpr int SCAN_CHUNK = 1024;  // elems per scan block (256 thr x 4)

__global__ __launch_bounds__(256) void zero_int_kernel(int* p, int n) {
  int i = blockIdx.x * 256 + threadIdx.x;
  int stride = gridDim.x * 256;
  for (; i < n; i += stride) p[i] = 0;
}

__global__ __launch_bounds__(256) void count_deg_kernel(
    const int* __restrict__ dst, int* __restrict__ deg, int E) {
  int e = blockIdx.x * 256 + threadIdx.x;
  if (e < E) atomicAdd(&deg[dst[e]], 1);
}

// per-chunk sums
__global__ __launch_bounds__(256) void scan_pass1_kernel(
    const int* __restrict__ deg, int* __restrict__ bsum, int n) {
  __shared__ int l[256];
  const int base = blockIdx.x * SCAN_CHUNK + threadIdx.x * 4;
  int s = 0;
#pragma unroll
  for (int j = 0; j < 4; ++j) {
    const int i = base + j;
    if (i < n) s += deg[i];
  }
  l[threadIdx.x] = s;
  __syncthreads();
  for (int off = 128; off > 0; off >>= 1) {
    if (threadIdx.x < off) l[threadIdx.x] += l[threadIdx.x + off];
    __syncthreads();
  }
  if (threadIdx.x == 0) bsum[blockIdx.x] = l[0];
}

// exclusive scan of chunk sums (nchunks ~ 98, single thread is fine)
__global__ void scan_pass2_kernel(int* bsum, int nchunks) {
  int run = 0;
  for (int i = 0; i < nchunks; ++i) {
    const int v = bsum[i];
    bsum[i] = run;
    run += v;
  }
}

// local exclusive scan + chunk offset -> rowptr AND cursor (cursor aliases deg;
// each thread reads its own deg elems before overwriting them).
__global__ __launch_bounds__(256) void scan_pass3_kernel(
    const int* __restrict__ deg, const int* __restrict__ bsum,
    int* __restrict__ rowptr, int* __restrict__ cursor, int n, int E) {
  __shared__ int l[256];
  const int base = blockIdx.x * SCAN_CHUNK + threadIdx.x * 4;
  int v[4];
  int s = 0;
#pragma unroll
  for (int j = 0; j < 4; ++j) {
    const int i = base + j;
    v[j] = (i < n) ? deg[i] : 0;
    s += v[j];
  }
  l[threadIdx.x] = s;
  __syncthreads();
  // Hillis-Steele inclusive scan
  for (int off = 1; off < 256; off <<= 1) {
    const int mine = l[threadIdx.x];
    const int add = (threadIdx.x >= off) ? l[threadIdx.x - off] : 0;
    __syncthreads();
    l[threadIdx.x] = mine + add;
    __syncthreads();
  }
  int run = bsum[blockIdx.x] + l[threadIdx.x] - s;  // exclusive
#pragma unroll
  for (int j = 0; j < 4; ++j) {
    const int i = base + j;
    if (i < n) {
      rowptr[i] = run;
      cursor[i] = run;
      run += v[j];
    }
  }
  if (blockIdx.x == 0 && threadIdx.x == 0) rowptr[n] = E;
}

__global__ __launch_bounds__(256) void bucket_kernel(
    const int* __restrict__ src, const int* __restrict__ dst,
    const float* __restrict__ ew, int* __restrict__ cursor,
    int2* __restrict__ csr, int E) {
  const int e = blockIdx.x * 256 + threadIdx.x;
  if (e >= E) return;
  const int d = dst[e];
  const int pos = atomicAdd(&cursor[d], 1);
  csr[pos] = make_int2(src[e], __float_as_int(ew[e]));
}

// in: [nrows x 128], W: [128 x NC] row-major, out: [nrows x NC]
template <int NC, bool RELU>
__global__ __launch_bounds__(256) void gemm_kernel(
    const float* __restrict__ in, const float* __restrict__ W,
    float* __restrict__ out, int nrows) {
  constexpr int K = 128;
  __shared__ float Wlds[K * NC];
  for (int i = threadIdx.x; i < K * NC / 4; i += 256) {
    ((float4*)Wlds)[i] = ((const float4*)W)[i];
  }
  __syncthreads();

  const int lane = threadIdx.x & 63;
  const int wave = threadIdx.x >> 6;
  const int r0 = blockIdx.x * 32 + wave * 8;

  for (int i = 0; i < 8; ++i) {
    const int r = r0 + i;
    if (r >= nrows) return;
    float xa = in[(long)r * K + lane];
    float xb = in[(long)r * K + 64 + lane];
    if (RELU) { xa = fmaxf(xa, 0.f); xb = fmaxf(xb, 0.f); }
    float acc0 = 0.f, acc1 = 0.f;
#pragma unroll
    for (int k = 0; k < 64; ++k) {
      const float xv = __shfl(xa, k, 64);
      acc0 = fmaf(xv, Wlds[k * NC + lane], acc0);
      if (NC == 128) acc1 = fmaf(xv, Wlds[k * NC + 64 + lane], acc1);
    }
#pragma unroll
    for (int k = 0; k < 64; ++k) {
      const float xv = __shfl(xb, k, 64);
      acc0 = fmaf(xv, Wlds[(64 + k) * NC + lane], acc0);
      if (NC == 128) acc1 = fmaf(xv, Wlds[(64 + k) * NC + 64 + lane], acc1);
    }
    out[(long)r * NC + lane] = acc0;
    if (NC == 128) out[(long)r * NC + 64 + lane] = acc1;
  }
}

// out[node] = bias + sum_{e in row(node)} w_e * t[src_e]   (wave per node)
template <int F>
__global__ __launch_bounds__(256) void gather_kernel(
    const float* __restrict__ t, const int2* __restrict__ csr,
    const int* __restrict__ rowptr, const float* __restrict__ bias,
    float* __restrict__ outp, int n) {
  const int lane = threadIdx.x & 63;
  const int node =
      __builtin_amdgcn_readfirstlane(blockIdx.x * 4 + (threadIdx.x >> 6));
  if (node >= n) return;
  const int beg = __builtin_amdgcn_readfirstlane(rowptr[node]);
  const int end = __builtin_amdgcn_readfirstlane(rowptr[node + 1]);

  if (F == 128) {
    float2 a0 = *(const float2*)&bias[lane * 2];
    float2 a1 = {0.f, 0.f};
    int e = beg;
    for (; e + 2 <= end; e += 2) {
      const int2 e0 = csr[e];
      const int2 e1 = csr[e + 1];
      const float w0 = __int_as_float(e0.y);
      const float w1 = __int_as_float(e1.y);
      const float2 v0 = *(const float2*)&t[(long)e0.x * 128 + lane * 2];
      const float2 v1 = *(const float2*)&t[(long)e1.x * 128 + lane * 2];
      a0.x = fmaf(v0.x, w0, a0.x);
      a0.y = fmaf(v0.y, w0, a0.y);
      a1.x = fmaf(v1.x, w1, a1.x);
      a1.y = fmaf(v1.y, w1, a1.y);
    }
    if (e < end) {
      const int2 e0 = csr[e];
      const float w0 = __int_as_float(e0.y);
      const float2 v0 = *(const float2*)&t[(long)e0.x * 128 + lane * 2];
      a0.x = fmaf(v0.x, w0, a0.x);
      a0.y = fmaf(v0.y, w0, a0.y);
    }
    a0.x += a1.x;
    a0.y += a1.y;
    *(float2*)&outp[(long)node * 128 + lane * 2] = a0;
  } else {
    float a0 = bias[lane];
    float a1 = 0.f;
    int e = beg;
    for (; e + 2 <= end; e += 2) {
      const int2 e0 = csr[e];
      const int2 e1 = csr[e + 1];
      const float v0 = t[(long)e0.x * 64 + lane];
      const float v1 = t[(long)e1.x * 64 + lane];
      a0 = fmaf(v0, __int_as_float(e0.y), a0);
      a1 = fmaf(v1, __int_as_float(e1.y), a1);
    }
    if (e < end) {
      const int2 e0 = csr[e];
      a0 = fmaf(t[(long)e0.x * 64 + lane], __int_as_float(e0.y), a0);
    }
    outp[(long)node * 64 + lane] = a0 + a1;
  }
}

extern "C" void kernel_launch(void* const* d_in, const int* in_sizes, int n_in,
                              void* d_out, int out_size, void* d_ws, size_t ws_size,
                              hipStream_t stream) {
  const float* x  = (const float*)d_in[0];
  const int*   ei = (const int*)d_in[1];
  const float* ew = (const float*)d_in[2];
  const float* W1 = (const float*)d_in[3];
  const float* b1 = (const float*)d_in[4];
  const float* W2 = (const float*)d_in[5];
  const float* b2 = (const float*)d_in[6];
  const float* W3 = (const float*)d_in[7];
  const float* b3 = (const float*)d_in[8];

  const int E = in_sizes[2];
  const int N = in_sizes[0] / 128;
  const int* src = ei;
  const int* dst = ei + E;

  // workspace layout (8B-aligned pieces)
  float* A = (float*)d_ws;                    // N*128 (GEMM out)
  float* B = A + (size_t)N * 128;             // N*128 (agg out / next in)
  int2* csr = (int2*)(B + (size_t)N * 128);   // E  (src, w) pairs
  int* rowptr = (int*)(csr + E);              // N+1
  int* cursor = rowptr + (N + 1);             // N  (aliases deg)
  int* bsum = cursor + N;                     // nchunks
  int* deg = cursor;

  const int nchunks = (N + SCAN_CHUNK - 1) / SCAN_CHUNK;
  const int eblocks = (E + 255) / 256;
  const int gemm_blocks = (N + 31) / 32;
  const int gather_blocks = (N + 3) / 4;

  // ---- build CSR (bucketed by dst) ----
  zero_int_kernel<<<256, 256, 0, stream>>>(deg, N);
  count_deg_kernel<<<eblocks, 256, 0, stream>>>(dst, deg, E);
  scan_pass1_kernel<<<nchunks, 256, 0, stream>>>(deg, bsum, N);
  scan_pass2_kernel<<<1, 1, 0, stream>>>(bsum, nchunks);
  scan_pass3_kernel<<<nchunks, 256, 0, stream>>>(deg, bsum, rowptr, cursor, N, E);
  bucket_kernel<<<eblocks, 256, 0, stream>>>(src, dst, ew, cursor, csr, E);

  // ---- layer 1: A = x@W1; B = b1 + gather(A) ----
  gemm_kernel<128, false><<<gemm_blocks, 256, 0, stream>>>(x, W1, A, N);
  gather_kernel<128><<<gather_blocks, 256, 0, stream>>>(A, csr, rowptr, b1, B, N);

  // ---- layer 2: A = relu(B)@W2; B = b2 + gather(A) ----
  gemm_kernel<128, true><<<gemm_blocks, 256, 0, stream>>>(B, W2, A, N);
  gather_kernel<128><<<gather_blocks, 256, 0, stream>>>(A, csr, rowptr, b2, B, N);

  // ---- layer 3: A = relu(B)@W3; out = b3 + gather(A) ----
  gemm_kernel<64, true><<<gemm_blocks, 256, 0, stream>>>(B, W3, A, N);
  gather_kernel<64><<<gather_blocks, 256, 0, stream>>>((const float*)A, csr, rowptr, b3,
                                                       (float*)d_out, E ? N : N);
}

// Round 3
// 450.683 us; speedup vs baseline: 8.1053x; 2.5897x over previous
//
#include <hip/hip_runtime.h>

// ---------------------------------------------------------------------------
// GCN 3-layer forward. Round 3:
//   - GEMMs -> bf16 MFMA (16x16x32), W pre-transposed+XOR-swizzled in ws,
//     staged to LDS (32KB), A-frags straight from global, fp32 accum.
//   - Intermediate features bf16 (relu fused into gather epilogue): halves
//     gather read traffic and GEMM input traffic.
//   - Aggregation: on-device CSR build + wave-per-node gather (unchanged).
// ---------------------------------------------------------------------------

typedef __attribute__((ext_vector_type(8))) short short8;
typedef __attribute__((ext_vector_type(4))) float f32x4;

__device__ __forceinline__ unsigned short f2bf(float f) {
  union { float f; unsigned u; } v; v.f = f;
  unsigned r = v.u + 0x7fffu + ((v.u >> 16) & 1u);  // RNE
  return (unsigned short)(r >> 16);
}
__device__ __forceinline__ float bf2f(unsigned short h) {
  union { unsigned u; float f; } v; v.u = (unsigned)h << 16;
  return v.f;
}

constexpr int SCAN_CHUNK = 1024;

// ---------------- CSR build (unchanged from round 2) ----------------
__global__ __launch_bounds__(256) void zero_int_kernel(int* p, int n) {
  int i = blockIdx.x * 256 + threadIdx.x;
  int stride = gridDim.x * 256;
  for (; i < n; i += stride) p[i] = 0;
}

__global__ __launch_bounds__(256) void count_deg_kernel(
    const int* __restrict__ dst, int* __restrict__ deg, int E) {
  int e = blockIdx.x * 256 + threadIdx.x;
  if (e < E) atomicAdd(&deg[dst[e]], 1);
}

__global__ __launch_bounds__(256) void scan_pass1_kernel(
    const int* __restrict__ deg, int* __restrict__ bsum, int n) {
  __shared__ int l[256];
  const int base = blockIdx.x * SCAN_CHUNK + threadIdx.x * 4;
  int s = 0;
#pragma unroll
  for (int j = 0; j < 4; ++j) {
    const int i = base + j;
    if (i < n) s += deg[i];
  }
  l[threadIdx.x] = s;
  __syncthreads();
  for (int off = 128; off > 0; off >>= 1) {
    if (threadIdx.x < off) l[threadIdx.x] += l[threadIdx.x + off];
    __syncthreads();
  }
  if (threadIdx.x == 0) bsum[blockIdx.x] = l[0];
}

__global__ void scan_pass2_kernel(int* bsum, int nchunks) {
  int run = 0;
  for (int i = 0; i < nchunks; ++i) {
    const int v = bsum[i];
    bsum[i] = run;
    run += v;
  }
}

__global__ __launch_bounds__(256) void scan_pass3_kernel(
    const int* __restrict__ deg, const int* __restrict__ bsum,
    int* __restrict__ rowptr, int* __restrict__ cursor, int n, int E) {
  __shared__ int l[256];
  const int base = blockIdx.x * SCAN_CHUNK + threadIdx.x * 4;
  int v[4];
  int s = 0;
#pragma unroll
  for (int j = 0; j < 4; ++j) {
    const int i = base + j;
    v[j] = (i < n) ? deg[i] : 0;
    s += v[j];
  }
  l[threadIdx.x] = s;
  __syncthreads();
  for (int off = 1; off < 256; off <<= 1) {
    const int mine = l[threadIdx.x];
    const int add = (threadIdx.x >= off) ? l[threadIdx.x - off] : 0;
    __syncthreads();
    l[threadIdx.x] = mine + add;
    __syncthreads();
  }
  int run = bsum[blockIdx.x] + l[threadIdx.x] - s;  // exclusive
#pragma unroll
  for (int j = 0; j < 4; ++j) {
    const int i = base + j;
    if (i < n) {
      rowptr[i] = run;
      cursor[i] = run;
      run += v[j];
    }
  }
  if (blockIdx.x == 0 && threadIdx.x == 0) rowptr[n] = E;
}

__global__ __launch_bounds__(256) void bucket_kernel(
    const int* __restrict__ src, const int* __restrict__ dst,
    const float* __restrict__ ew, int* __restrict__ cursor,
    int2* __restrict__ csr, int E) {
  const int e = blockIdx.x * 256 + threadIdx.x;
  if (e >= E) return;
  const int d = dst[e];
  const int pos = atomicAdd(&cursor[d], 1);
  csr[pos] = make_int2(src[e], __float_as_int(ew[e]));
}

// ---------------- W prep: fp32 [128][NC] -> bf16 WT[n][k] with XOR swizzle
// WT byte layout: n*256 + ((2k) ^ ((n&7)<<4))  (k = 0..127)
__global__ __launch_bounds__(256) void prep_w_kernel(
    const float* __restrict__ W1, const float* __restrict__ W2,
    const float* __restrict__ W3, unsigned short* __restrict__ WT1,
    unsigned short* __restrict__ WT2, unsigned short* __restrict__ WT3) {
  const int id = blockIdx.x * 256 + threadIdx.x;
  const float* W;
  unsigned short* WT;
  int NC, idx;
  if (id < 16384) { W = W1; WT = WT1; NC = 128; idx = id; }
  else if (id < 32768) { W = W2; WT = WT2; NC = 128; idx = id - 16384; }
  else if (id < 40960) { W = W3; WT = WT3; NC = 64; idx = id - 32768; }
  else return;
  const int k = idx / NC, n = idx % NC;
  *(unsigned short*)((char*)WT + n * 256 + ((2 * k) ^ ((n & 7) << 4))) =
      f2bf(W[idx]);
}

// ---------------- bf16 MFMA GEMM: in [nrows x 128] -> out [nrows x NC] bf16
// Block: 256 thr = 4 waves, 64 rows; wave = 16 rows x NC cols, K swept fully.
template <int NC, bool IN_F32>
__global__ __launch_bounds__(256) void gemm_mfma_kernel(
    const void* __restrict__ in, const unsigned short* __restrict__ WT,
    unsigned short* __restrict__ outp, int nrows) {
  constexpr int NT = NC / 16;
  __shared__ unsigned short Wlds[NC * 128];
  {  // linear 32KB/16KB stage (layout already swizzled in ws)
    const float4* wsrc = (const float4*)WT;
    float4* wdst = (float4*)Wlds;
    for (int i = threadIdx.x; i < NC * 256 / 16; i += 256) wdst[i] = wsrc[i];
  }
  __syncthreads();

  const int lane = threadIdx.x & 63;
  const int wave = threadIdx.x >> 6;
  const int nl = lane & 15;          // A-row-in-tile / B-col-in-tile
  const int kl = (lane >> 4) * 8;    // k sub-offset
  const int rb = blockIdx.x * 64 + wave * 16;
  const int ra = min(rb + nl, nrows - 1);  // clamped A row
  const int swz = (nl & 7) << 4;
  const char* wbase = (const char*)Wlds + nl * 256;

  f32x4 acc[NT] = {};

#pragma unroll
  for (int k0 = 0; k0 < 128; k0 += 32) {
    short8 a;
    if (IN_F32) {
      const float* xp = (const float*)in + (size_t)ra * 128 + k0 + kl;
      const float4 x0 = *(const float4*)xp;
      const float4 x1 = *(const float4*)(xp + 4);
      a[0] = (short)f2bf(x0.x); a[1] = (short)f2bf(x0.y);
      a[2] = (short)f2bf(x0.z); a[3] = (short)f2bf(x0.w);
      a[4] = (short)f2bf(x1.x); a[5] = (short)f2bf(x1.y);
      a[6] = (short)f2bf(x1.z); a[7] = (short)f2bf(x1.w);
    } else {
      a = *(const short8*)((const unsigned short*)in + (size_t)ra * 128 + k0 + kl);
    }
    const int koff = (2 * (k0 + kl)) ^ swz;
#pragma unroll
    for (int ct = 0; ct < NT; ++ct) {
      const short8 b = *(const short8*)(wbase + ct * 4096 + koff);
      acc[ct] = __builtin_amdgcn_mfma_f32_16x16x32_bf16(a, b, acc[ct], 0, 0, 0);
    }
  }

  // D: col = ct*16 + (lane&15), row = rb + (lane>>4)*4 + j
  const int r0 = rb + (lane >> 4) * 4;
#pragma unroll
  for (int ct = 0; ct < NT; ++ct) {
#pragma unroll
    for (int j = 0; j < 4; ++j) {
      const int r = r0 + j;
      if (r < nrows) outp[(size_t)r * NC + ct * 16 + nl] = f2bf(acc[ct][j]);
    }
  }
}

// ---------------- gather: out[node] = (+relu,bf16 | f32) bias + sum w_e*t[src]
template <bool BF16OUT>
__global__ __launch_bounds__(256) void gather128_kernel(
    const unsigned short* __restrict__ t, const int2* __restrict__ csr,
    const int* __restrict__ rowptr, const float* __restrict__ bias,
    void* __restrict__ outp, int n) {
  const int lane = threadIdx.x & 63;
  const int node = blockIdx.x * 4 + (threadIdx.x >> 6);
  if (node >= n) return;
  const int beg = __builtin_amdgcn_readfirstlane(rowptr[node]);
  const int end = __builtin_amdgcn_readfirstlane(rowptr[node + 1]);

  float2 a0 = *(const float2*)&bias[lane * 2];
  float2 a1 = {0.f, 0.f};
  int e = beg;
  for (; e + 2 <= end; e += 2) {
    const int2 e0 = csr[e];
    const int2 e1 = csr[e + 1];
    const unsigned v0 = *(const unsigned*)&t[(size_t)e0.x * 128 + lane * 2];
    const unsigned v1 = *(const unsigned*)&t[(size_t)e1.x * 128 + lane * 2];
    const float w0 = __int_as_float(e0.y);
    const float w1 = __int_as_float(e1.y);
    a0.x = fmaf(bf2f((unsigned short)v0), w0, a0.x);
    a0.y = fmaf(bf2f((unsigned short)(v0 >> 16)), w0, a0.y);
    a1.x = fmaf(bf2f((unsigned short)v1), w1, a1.x);
    a1.y = fmaf(bf2f((unsigned short)(v1 >> 16)), w1, a1.y);
  }
  if (e < end) {
    const int2 e0 = csr[e];
    const unsigned v0 = *(const unsigned*)&t[(size_t)e0.x * 128 + lane * 2];
    const float w0 = __int_as_float(e0.y);
    a0.x = fmaf(bf2f((unsigned short)v0), w0, a0.x);
    a0.y = fmaf(bf2f((unsigned short)(v0 >> 16)), w0, a0.y);
  }
  a0.x += a1.x;
  a0.y += a1.y;
  if (BF16OUT) {
    a0.x = fmaxf(a0.x, 0.f);
    a0.y = fmaxf(a0.y, 0.f);
    const unsigned pk = (unsigned)f2bf(a0.x) | ((unsigned)f2bf(a0.y) << 16);
    *(unsigned*)((unsigned short*)outp + (size_t)node * 128 + lane * 2) = pk;
  } else {
    *(float2*)((float*)outp + (size_t)node * 128 + lane * 2) = a0;
  }
}

__global__ __launch_bounds__(256) void gather64_kernel(
    const unsigned short* __restrict__ t, const int2* __restrict__ csr,
    const int* __restrict__ rowptr, const float* __restrict__ bias,
    float* __restrict__ outp, int n) {
  const int lane = threadIdx.x & 63;
  const int node = blockIdx.x * 4 + (threadIdx.x >> 6);
  if (node >= n) return;
  const int beg = __builtin_amdgcn_readfirstlane(rowptr[node]);
  const int end = __builtin_amdgcn_readfirstlane(rowptr[node + 1]);
  float a0 = bias[lane], a1 = 0.f;
  int e = beg;
  for (; e + 2 <= end; e += 2) {
    const int2 e0 = csr[e];
    const int2 e1 = csr[e + 1];
    a0 = fmaf(bf2f(t[(size_t)e0.x * 64 + lane]), __int_as_float(e0.y), a0);
    a1 = fmaf(bf2f(t[(size_t)e1.x * 64 + lane]), __int_as_float(e1.y), a1);
  }
  if (e < end) {
    const int2 e0 = csr[e];
    a0 = fmaf(bf2f(t[(size_t)e0.x * 64 + lane]), __int_as_float(e0.y), a0);
  }
  outp[(size_t)node * 64 + lane] = a0 + a1;
}

// ---------------------------------------------------------------------------
extern "C" void kernel_launch(void* const* d_in, const int* in_sizes, int n_in,
                              void* d_out, int out_size, void* d_ws, size_t ws_size,
                              hipStream_t stream) {
  const float* x  = (const float*)d_in[0];
  const int*   ei = (const int*)d_in[1];
  const float* ew = (const float*)d_in[2];
  const float* W1 = (const float*)d_in[3];
  const float* b1 = (const float*)d_in[4];
  const float* W2 = (const float*)d_in[5];
  const float* b2 = (const float*)d_in[6];
  const float* W3 = (const float*)d_in[7];
  const float* b3 = (const float*)d_in[8];

  const int E = in_sizes[2];
  const int N = in_sizes[0] / 128;
  const int* src = ei;
  const int* dst = ei + E;

  // workspace layout
  unsigned short* WT1 = (unsigned short*)d_ws;        // 16384
  unsigned short* WT2 = WT1 + 16384;                  // 16384
  unsigned short* WT3 = WT2 + 16384;                  // 8192
  unsigned short* t = WT3 + 8192;                     // N*128 bf16
  unsigned short* g = t + (size_t)N * 128;            // N*128 bf16
  int2* csr = (int2*)(g + (size_t)N * 128);           // E
  int* rowptr = (int*)(csr + E);                      // N+1
  int* cursor = rowptr + (N + 1);                     // N (aliases deg)
  int* bsum = cursor + N;                             // nchunks
  int* deg = cursor;

  const int nchunks = (N + SCAN_CHUNK - 1) / SCAN_CHUNK;
  const int eblocks = (E + 255) / 256;
  const int gemm_blocks = (N + 63) / 64;
  const int gather_blocks = (N + 3) / 4;

  // ---- W prep + CSR build ----
  prep_w_kernel<<<160, 256, 0, stream>>>(W1, W2, W3, WT1, WT2, WT3);
  zero_int_kernel<<<256, 256, 0, stream>>>(deg, N);
  count_deg_kernel<<<eblocks, 256, 0, stream>>>(dst, deg, E);
  scan_pass1_kernel<<<nchunks, 256, 0, stream>>>(deg, bsum, N);
  scan_pass2_kernel<<<1, 1, 0, stream>>>(bsum, nchunks);
  scan_pass3_kernel<<<nchunks, 256, 0, stream>>>(deg, bsum, rowptr, cursor, N, E);
  bucket_kernel<<<eblocks, 256, 0, stream>>>(src, dst, ew, cursor, csr, E);

  // ---- layer 1: t = bf16(x@W1); g = bf16(relu(b1 + gather(t))) ----
  gemm_mfma_kernel<128, true><<<gemm_blocks, 256, 0, stream>>>(x, WT1, t, N);
  gather128_kernel<true><<<gather_blocks, 256, 0, stream>>>(t, csr, rowptr, b1, g, N);

  // ---- layer 2: t = bf16(g@W2); g = bf16(relu(b2 + gather(t))) ----
  gemm_mfma_kernel<128, false><<<gemm_blocks, 256, 0, stream>>>(g, WT2, t, N);
  gather128_kernel<true><<<gather_blocks, 256, 0, stream>>>(t, csr, rowptr, b2, g, N);

  // ---- layer 3: t = bf16(g@W3); out = b3 + gather(t) (fp32) ----
  gemm_mfma_kernel<64, false><<<gemm_blocks, 256, 0, stream>>>(g, WT3, t, N);
  gather64_kernel<<<gather_blocks, 256, 0, stream>>>(t, csr, rowptr, b3,
                                                     (float*)d_out, N);
}

// Round 4
// 402.147 us; speedup vs baseline: 9.0836x; 1.1207x over previous
//
#include <hip/hip_runtime.h>

// ---------------------------------------------------------------------------
// GCN 3-layer forward. Round 4:
//   - Non-temporal loads on all read-once streams (bucket/count_deg edge
//     arrays, gather csr stream) so L2 keeps (a) dirty scatter lines in the
//     CSR build -> partial-line writes merge, (b) the gathered feature table.
//   - Gather unrolled 4-wide (4 independent accumulators) for more MLP.
//   - Otherwise round-3 structure: bf16 MFMA GEMMs (W pre-swizzled in ws),
//     bf16 intermediate features, on-device CSR build, fused bias/relu.
// ---------------------------------------------------------------------------

typedef __attribute__((ext_vector_type(8))) short short8;
typedef __attribute__((ext_vector_type(4))) float f32x4;

__device__ __forceinline__ unsigned short f2bf(float f) {
  union { float f; unsigned u; } v; v.f = f;
  unsigned r = v.u + 0x7fffu + ((v.u >> 16) & 1u);  // RNE
  return (unsigned short)(r >> 16);
}
__device__ __forceinline__ float bf2f(unsigned short h) {
  union { unsigned u; float f; } v; v.u = (unsigned)h << 16;
  return v.f;
}

constexpr int SCAN_CHUNK = 1024;

// ---------------- CSR build ----------------
__global__ __launch_bounds__(256) void zero_int_kernel(int* p, int n) {
  int i = blockIdx.x * 256 + threadIdx.x;
  int stride = gridDim.x * 256;
  for (; i < n; i += stride) p[i] = 0;
}

__global__ __launch_bounds__(256) void count_deg_kernel(
    const int* __restrict__ dst, int* __restrict__ deg, int E) {
  int e = blockIdx.x * 256 + threadIdx.x;
  if (e < E) atomicAdd(&deg[__builtin_nontemporal_load(dst + e)], 1);
}

__global__ __launch_bounds__(256) void scan_pass1_kernel(
    const int* __restrict__ deg, int* __restrict__ bsum, int n) {
  __shared__ int l[256];
  const int base = blockIdx.x * SCAN_CHUNK + threadIdx.x * 4;
  int s = 0;
#pragma unroll
  for (int j = 0; j < 4; ++j) {
    const int i = base + j;
    if (i < n) s += deg[i];
  }
  l[threadIdx.x] = s;
  __syncthreads();
  for (int off = 128; off > 0; off >>= 1) {
    if (threadIdx.x < off) l[threadIdx.x] += l[threadIdx.x + off];
    __syncthreads();
  }
  if (threadIdx.x == 0) bsum[blockIdx.x] = l[0];
}

__global__ void scan_pass2_kernel(int* bsum, int nchunks) {
  int run = 0;
  for (int i = 0; i < nchunks; ++i) {
    const int v = bsum[i];
    bsum[i] = run;
    run += v;
  }
}

__global__ __launch_bounds__(256) void scan_pass3_kernel(
    const int* __restrict__ deg, const int* __restrict__ bsum,
    int* __restrict__ rowptr, int* __restrict__ cursor, int n, int E) {
  __shared__ int l[256];
  const int base = blockIdx.x * SCAN_CHUNK + threadIdx.x * 4;
  int v[4];
  int s = 0;
#pragma unroll
  for (int j = 0; j < 4; ++j) {
    const int i = base + j;
    v[j] = (i < n) ? deg[i] : 0;
    s += v[j];
  }
  l[threadIdx.x] = s;
  __syncthreads();
  for (int off = 1; off < 256; off <<= 1) {
    const int mine = l[threadIdx.x];
    const int add = (threadIdx.x >= off) ? l[threadIdx.x - off] : 0;
    __syncthreads();
    l[threadIdx.x] = mine + add;
    __syncthreads();
  }
  int run = bsum[blockIdx.x] + l[threadIdx.x] - s;  // exclusive
#pragma unroll
  for (int j = 0; j < 4; ++j) {
    const int i = base + j;
    if (i < n) {
      rowptr[i] = run;
      cursor[i] = run;
      run += v[j];
    }
  }
  if (blockIdx.x == 0 && threadIdx.x == 0) rowptr[n] = E;
}

__global__ __launch_bounds__(256) void bucket_kernel(
    const int* __restrict__ src, const int* __restrict__ dst,
    const float* __restrict__ ew, int* __restrict__ cursor,
    int2* __restrict__ csr, int E) {
  const int e = blockIdx.x * 256 + threadIdx.x;
  if (e >= E) return;
  const int d = __builtin_nontemporal_load(dst + e);
  const int s = __builtin_nontemporal_load(src + e);
  const float wt = __builtin_nontemporal_load(ew + e);
  const int pos = atomicAdd(&cursor[d], 1);
  csr[pos] = make_int2(s, __float_as_int(wt));
}

// ---------------- W prep: fp32 [128][NC] -> bf16 WT[n][k] with XOR swizzle
__global__ __launch_bounds__(256) void prep_w_kernel(
    const float* __restrict__ W1, const float* __restrict__ W2,
    const float* __restrict__ W3, unsigned short* __restrict__ WT1,
    unsigned short* __restrict__ WT2, unsigned short* __restrict__ WT3) {
  const int id = blockIdx.x * 256 + threadIdx.x;
  const float* W;
  unsigned short* WT;
  int NC, idx;
  if (id < 16384) { W = W1; WT = WT1; NC = 128; idx = id; }
  else if (id < 32768) { W = W2; WT = WT2; NC = 128; idx = id - 16384; }
  else if (id < 40960) { W = W3; WT = WT3; NC = 64; idx = id - 32768; }
  else return;
  const int k = idx / NC, n = idx % NC;
  *(unsigned short*)((char*)WT + n * 256 + ((2 * k) ^ ((n & 7) << 4))) =
      f2bf(W[idx]);
}

// ---------------- bf16 MFMA GEMM ----------------
template <int NC, bool IN_F32>
__global__ __launch_bounds__(256) void gemm_mfma_kernel(
    const void* __restrict__ in, const unsigned short* __restrict__ WT,
    unsigned short* __restrict__ outp, int nrows) {
  constexpr int NT = NC / 16;
  __shared__ unsigned short Wlds[NC * 128];
  {
    const float4* wsrc = (const float4*)WT;
    float4* wdst = (float4*)Wlds;
    for (int i = threadIdx.x; i < NC * 256 / 16; i += 256) wdst[i] = wsrc[i];
  }
  __syncthreads();

  const int lane = threadIdx.x & 63;
  const int wave = threadIdx.x >> 6;
  const int nl = lane & 15;
  const int kl = (lane >> 4) * 8;
  const int rb = blockIdx.x * 64 + wave * 16;
  const int ra = min(rb + nl, nrows - 1);
  const int swz = (nl & 7) << 4;
  const char* wbase = (const char*)Wlds + nl * 256;

  f32x4 acc[NT] = {};

#pragma unroll
  for (int k0 = 0; k0 < 128; k0 += 32) {
    short8 a;
    if (IN_F32) {
      const float* xp = (const float*)in + (size_t)ra * 128 + k0 + kl;
      const float4 x0 = *(const float4*)xp;
      const float4 x1 = *(const float4*)(xp + 4);
      a[0] = (short)f2bf(x0.x); a[1] = (short)f2bf(x0.y);
      a[2] = (short)f2bf(x0.z); a[3] = (short)f2bf(x0.w);
      a[4] = (short)f2bf(x1.x); a[5] = (short)f2bf(x1.y);
      a[6] = (short)f2bf(x1.z); a[7] = (short)f2bf(x1.w);
    } else {
      a = *(const short8*)((const unsigned short*)in + (size_t)ra * 128 + k0 + kl);
    }
    const int koff = (2 * (k0 + kl)) ^ swz;
#pragma unroll
    for (int ct = 0; ct < NT; ++ct) {
      const short8 b = *(const short8*)(wbase + ct * 4096 + koff);
      acc[ct] = __builtin_amdgcn_mfma_f32_16x16x32_bf16(a, b, acc[ct], 0, 0, 0);
    }
  }

  const int r0 = rb + (lane >> 4) * 4;
#pragma unroll
  for (int ct = 0; ct < NT; ++ct) {
#pragma unroll
    for (int j = 0; j < 4; ++j) {
      const int r = r0 + j;
      if (r < nrows) outp[(size_t)r * NC + ct * 16 + nl] = f2bf(acc[ct][j]);
    }
  }
}

// ---------------- gathers (4-wide unroll, NT csr stream) ----------------
__device__ __forceinline__ void edge_unpack(long c, int& s, float& w) {
  s = (int)c;
  w = __int_as_float((int)(c >> 32));
}

template <bool BF16OUT>
__global__ __launch_bounds__(256) void gather128_kernel(
    const unsigned short* __restrict__ t, const long* __restrict__ csr,
    const int* __restrict__ rowptr, const float* __restrict__ bias,
    void* __restrict__ outp, int n) {
  const int lane = threadIdx.x & 63;
  const int node = blockIdx.x * 4 + (threadIdx.x >> 6);
  if (node >= n) return;
  const int beg = __builtin_amdgcn_readfirstlane(rowptr[node]);
  const int end = __builtin_amdgcn_readfirstlane(rowptr[node + 1]);

  float2 a0 = *(const float2*)&bias[lane * 2];
  float2 a1 = {0.f, 0.f}, a2 = {0.f, 0.f}, a3 = {0.f, 0.f};
  int e = beg;
  for (; e + 4 <= end; e += 4) {
    int s0, s1, s2, s3;
    float w0, w1, w2, w3;
    edge_unpack(__builtin_nontemporal_load(csr + e), s0, w0);
    edge_unpack(__builtin_nontemporal_load(csr + e + 1), s1, w1);
    edge_unpack(__builtin_nontemporal_load(csr + e + 2), s2, w2);
    edge_unpack(__builtin_nontemporal_load(csr + e + 3), s3, w3);
    const unsigned v0 = *(const unsigned*)&t[(size_t)s0 * 128 + lane * 2];
    const unsigned v1 = *(const unsigned*)&t[(size_t)s1 * 128 + lane * 2];
    const unsigned v2 = *(const unsigned*)&t[(size_t)s2 * 128 + lane * 2];
    const unsigned v3 = *(const unsigned*)&t[(size_t)s3 * 128 + lane * 2];
    a0.x = fmaf(bf2f((unsigned short)v0), w0, a0.x);
    a0.y = fmaf(bf2f((unsigned short)(v0 >> 16)), w0, a0.y);
    a1.x = fmaf(bf2f((unsigned short)v1), w1, a1.x);
    a1.y = fmaf(bf2f((unsigned short)(v1 >> 16)), w1, a1.y);
    a2.x = fmaf(bf2f((unsigned short)v2), w2, a2.x);
    a2.y = fmaf(bf2f((unsigned short)(v2 >> 16)), w2, a2.y);
    a3.x = fmaf(bf2f((unsigned short)v3), w3, a3.x);
    a3.y = fmaf(bf2f((unsigned short)(v3 >> 16)), w3, a3.y);
  }
  for (; e < end; ++e) {
    int s0; float w0;
    edge_unpack(__builtin_nontemporal_load(csr + e), s0, w0);
    const unsigned v0 = *(const unsigned*)&t[(size_t)s0 * 128 + lane * 2];
    a0.x = fmaf(bf2f((unsigned short)v0), w0, a0.x);
    a0.y = fmaf(bf2f((unsigned short)(v0 >> 16)), w0, a0.y);
  }
  a0.x += a1.x + a2.x + a3.x;
  a0.y += a1.y + a2.y + a3.y;
  if (BF16OUT) {
    a0.x = fmaxf(a0.x, 0.f);
    a0.y = fmaxf(a0.y, 0.f);
    const unsigned pk = (unsigned)f2bf(a0.x) | ((unsigned)f2bf(a0.y) << 16);
    *(unsigned*)((unsigned short*)outp + (size_t)node * 128 + lane * 2) = pk;
  } else {
    *(float2*)((float*)outp + (size_t)node * 128 + lane * 2) = a0;
  }
}

__global__ __launch_bounds__(256) void gather64_kernel(
    const unsigned short* __restrict__ t, const long* __restrict__ csr,
    const int* __restrict__ rowptr, const float* __restrict__ bias,
    float* __restrict__ outp, int n) {
  const int lane = threadIdx.x & 63;
  const int node = blockIdx.x * 4 + (threadIdx.x >> 6);
  if (node >= n) return;
  const int beg = __builtin_amdgcn_readfirstlane(rowptr[node]);
  const int end = __builtin_amdgcn_readfirstlane(rowptr[node + 1]);
  float a0 = bias[lane], a1 = 0.f, a2 = 0.f, a3 = 0.f;
  int e = beg;
  for (; e + 4 <= end; e += 4) {
    int s0, s1, s2, s3;
    float w0, w1, w2, w3;
    edge_unpack(__builtin_nontemporal_load(csr + e), s0, w0);
    edge_unpack(__builtin_nontemporal_load(csr + e + 1), s1, w1);
    edge_unpack(__builtin_nontemporal_load(csr + e + 2), s2, w2);
    edge_unpack(__builtin_nontemporal_load(csr + e + 3), s3, w3);
    a0 = fmaf(bf2f(t[(size_t)s0 * 64 + lane]), w0, a0);
    a1 = fmaf(bf2f(t[(size_t)s1 * 64 + lane]), w1, a1);
    a2 = fmaf(bf2f(t[(size_t)s2 * 64 + lane]), w2, a2);
    a3 = fmaf(bf2f(t[(size_t)s3 * 64 + lane]), w3, a3);
  }
  for (; e < end; ++e) {
    int s0; float w0;
    edge_unpack(__builtin_nontemporal_load(csr + e), s0, w0);
    a0 = fmaf(bf2f(t[(size_t)s0 * 64 + lane]), w0, a0);
  }
  outp[(size_t)node * 64 + lane] = a0 + a1 + a2 + a3;
}

// ---------------------------------------------------------------------------
extern "C" void kernel_launch(void* const* d_in, const int* in_sizes, int n_in,
                              void* d_out, int out_size, void* d_ws, size_t ws_size,
                              hipStream_t stream) {
  const float* x  = (const float*)d_in[0];
  const int*   ei = (const int*)d_in[1];
  const float* ew = (const float*)d_in[2];
  const float* W1 = (const float*)d_in[3];
  const float* b1 = (const float*)d_in[4];
  const float* W2 = (const float*)d_in[5];
  const float* b2 = (const float*)d_in[6];
  const float* W3 = (const float*)d_in[7];
  const float* b3 = (const float*)d_in[8];

  const int E = in_sizes[2];
  const int N = in_sizes[0] / 128;
  const int* src = ei;
  const int* dst = ei + E;

  unsigned short* WT1 = (unsigned short*)d_ws;        // 16384
  unsigned short* WT2 = WT1 + 16384;                  // 16384
  unsigned short* WT3 = WT2 + 16384;                  // 8192
  unsigned short* t = WT3 + 8192;                     // N*128 bf16
  unsigned short* g = t + (size_t)N * 128;            // N*128 bf16
  int2* csr = (int2*)(g + (size_t)N * 128);           // E
  int* rowptr = (int*)(csr + E);                      // N+1
  int* cursor = rowptr + (N + 1);                     // N (aliases deg)
  int* bsum = cursor + N;                             // nchunks
  int* deg = cursor;

  const int nchunks = (N + SCAN_CHUNK - 1) / SCAN_CHUNK;
  const int eblocks = (E + 255) / 256;
  const int gemm_blocks = (N + 63) / 64;
  const int gather_blocks = (N + 3) / 4;

  prep_w_kernel<<<160, 256, 0, stream>>>(W1, W2, W3, WT1, WT2, WT3);
  zero_int_kernel<<<256, 256, 0, stream>>>(deg, N);
  count_deg_kernel<<<eblocks, 256, 0, stream>>>(dst, deg, E);
  scan_pass1_kernel<<<nchunks, 256, 0, stream>>>(deg, bsum, N);
  scan_pass2_kernel<<<1, 1, 0, stream>>>(bsum, nchunks);
  scan_pass3_kernel<<<nchunks, 256, 0, stream>>>(deg, bsum, rowptr, cursor, N, E);
  bucket_kernel<<<eblocks, 256, 0, stream>>>(src, dst, ew, cursor, csr, E);

  gemm_mfma_kernel<128, true><<<gemm_blocks, 256, 0, stream>>>(x, WT1, t, N);
  gather128_kernel<true><<<gather_blocks, 256, 0, stream>>>(
      t, (const long*)csr, rowptr, b1, g, N);

  gemm_mfma_kernel<128, false><<<gemm_blocks, 256, 0, stream>>>(g, WT2, t, N);
  gather128_kernel<true><<<gather_blocks, 256, 0, stream>>>(
      t, (const long*)csr, rowptr, b2, g, N);

  gemm_mfma_kernel<64, false><<<gemm_blocks, 256, 0, stream>>>(g, WT3, t, N);
  gather64_kernel<<<gather_blocks, 256, 0, stream>>>(
      t, (const long*)csr, rowptr, b3, (float*)d_out, N);
}